// Round 1
// 41.439 us; speedup vs baseline: 1.7353x; 1.7353x over previous
//
#include <hip/hip_runtime.h>
#include <stdint.h>

#define IN_F   4096
#define OUT_F  11008
#define C32    5504     // packed dwords per k-row
#define LDST   72       // ushorts per LDS column row (64 k + 8 pad; 144B = 16B-aligned)
#define KHALF  2048     // k per block (K-split 2)
#define NST    32       // stages per block, 64 k each

typedef __attribute__((ext_vector_type(8))) _Float16 half8;
typedef __attribute__((ext_vector_type(4))) float floatx4;

// single-instruction f32 pair -> packed fp16 (RTZ)
static __device__ __forceinline__ uint32_t pkh(float a, float b) {
    auto h = __builtin_amdgcn_cvt_pkrtz(a, b);
    union { decltype(h) v; uint32_t u; } r; r.v = h; return r.u;
}

// Prep: zero the output (atomic K-split epilogue needs it) and convert
// x f32[64][4096] -> fp16 pairs in workspace (removes the per-stage A
// re-conversion that every block redundantly performed).
__global__ __launch_bounds__(256) void prep_kernel(
    const float* __restrict__ x, uint32_t* __restrict__ xh, float4* __restrict__ out4)
{
    int tid = blockIdx.x * 256 + threadIdx.x;
    if (tid < (64 * OUT_F / 4)) out4[tid] = make_float4(0.f, 0.f, 0.f, 0.f);
    if (tid < (64 * IN_F / 2)) {
        float2 v = ((const float2*)x)[tid];
        xh[tid] = pkh(v.x, v.y);
    }
}

// 256 thr = 4 waves. Block tile: 64 rows (all tokens) x 32 cols, K = 2048 (half).
// grid = (344, 2): K-split 2 -> 688 blocks, partial sums atomically added.
// Pipeline: register prefetch 2 stages ahead; raw s_barrier with lgkmcnt(0)
// only, so weight loads stay in flight across the barrier (counted-vmcnt idiom).
__global__ __launch_bounds__(256, 4) void int4_gemm_kernel(
    const int*      __restrict__ wp,      // [4096][5504] (byte in low 8 bits)
    const float*    __restrict__ wscale,  // f32 [32][11008]
    const float*    __restrict__ wzero,   // f32 [32][11008]
    const uint32_t* __restrict__ xh,      // fp16 pairs [64][4096/2]
    float*          __restrict__ out)     // f32 [64][11008]
{
    __shared__ float4 tab[16 * 16];                    // (s_e, z*s_e, s_o, z*s_o): 4 KB
    __shared__ __align__(16) ushort bld[2][32 * LDST]; // 2 x 4.5 KB, B[col][k] fp16

    const int tid   = threadIdx.x;
    const int col0  = blockIdx.x * 32;
    const int ky    = blockIdx.y;
    const int kbase = ky * KHALF;

    // staging role: thread owns dword-col c (out cols 2c, 2c+1), k-rows kb..kb+3
    const int c  = tid & 15;
    const int kb = (tid >> 4) * 4;
    const int ce = 2 * c, co = ce + 1;
    const int* wbase = wp + (size_t)(kbase + kb) * C32 + (col0 >> 1) + c;

    // MFMA role
    const int wave = tid >> 6;
    const int lane = tid & 63;
    const int g    = lane >> 4;            // k-group within fragment
    const int bc0  = lane & 15;            // B col (sub-tile 0)
    const int bc1  = bc0 + 16;
    const uint32_t* xbase = xh + (size_t)(wave * 16 + bc0) * (IN_F / 2) + (kbase >> 1) + g * 4;

    // (scale, zero*scale) table: 16 local k-groups x 16 col-pairs, 1 entry/thread
    {
        int gg = tid >> 4, cp = tid & 15;
        size_t b = (size_t)(ky * 16 + gg) * OUT_F + col0 + 2 * cp;
        float se = wscale[b], so = wscale[b + 1];
        float ze = wzero[b],  zo = wzero[b + 1];
        tab[tid] = make_float4(se, ze * se, so, zo * so);
    }

    floatx4 acc0 = {0.f, 0.f, 0.f, 0.f}, acc1 = {0.f, 0.f, 0.f, 0.f};

    struct Pref { uint32_t q0, q1, q2, q3; };
    auto issue = [&](int st) {
        const int* p = wbase + (size_t)st * (64 * (size_t)C32);
        Pref P;
        P.q0 = (uint32_t)p[0];
        P.q1 = (uint32_t)p[C32];
        P.q2 = (uint32_t)p[2 * C32];
        P.q3 = (uint32_t)p[3 * C32];
        return P;
    };

    auto dq_write = [&](ushort* buf, const Pref& P, int st) {
        float4 t = tab[((st >> 1) << 4) + c];          // local group = st/2
        float l0 = fmaf((float)( P.q0        & 15u), t.x, -t.y);
        float l1 = fmaf((float)( P.q1        & 15u), t.x, -t.y);
        float l2 = fmaf((float)( P.q2        & 15u), t.x, -t.y);
        float l3 = fmaf((float)( P.q3        & 15u), t.x, -t.y);
        float h0 = fmaf((float)((P.q0 >> 4)  & 15u), t.z, -t.w);
        float h1 = fmaf((float)((P.q1 >> 4)  & 15u), t.z, -t.w);
        float h2 = fmaf((float)((P.q2 >> 4)  & 15u), t.z, -t.w);
        float h3 = fmaf((float)((P.q3 >> 4)  & 15u), t.z, -t.w);
        *(uint2*)(buf + ce * LDST + kb) = make_uint2(pkh(l0, l1), pkh(l2, l3));
        *(uint2*)(buf + co * LDST + kb) = make_uint2(pkh(h0, h1), pkh(h2, h3));
    };

    auto compute = [&](const ushort* buf, int st) {
        union { uint4 u; half8 h; } a0, a1;
        a0.u = *(const uint4*)(xbase + (size_t)st * 32);        // k-half 0 (8 fp16)
        a1.u = *(const uint4*)(xbase + (size_t)st * 32 + 16);   // k-half 1
        half8 B00 = *(const half8*)(buf + bc0 * LDST + g * 8);
        half8 B01 = *(const half8*)(buf + bc0 * LDST + 32 + g * 8);
        half8 B10 = *(const half8*)(buf + bc1 * LDST + g * 8);
        half8 B11 = *(const half8*)(buf + bc1 * LDST + 32 + g * 8);
        acc0 = __builtin_amdgcn_mfma_f32_16x16x32_f16(a0.h, B00, acc0, 0, 0, 0);
        acc1 = __builtin_amdgcn_mfma_f32_16x16x32_f16(a0.h, B10, acc1, 0, 0, 0);
        acc0 = __builtin_amdgcn_mfma_f32_16x16x32_f16(a1.h, B01, acc0, 0, 0, 0);
        acc1 = __builtin_amdgcn_mfma_f32_16x16x32_f16(a1.h, B11, acc1, 0, 0, 0);
    };

    Pref P = issue(0);
    __syncthreads();                 // tab ready (one-time full drain is fine)
    dq_write(bld[0], P, 0);
    P = issue(1);
    asm volatile("s_waitcnt lgkmcnt(0)");
    __builtin_amdgcn_s_barrier();    // bld[0] ready; issue(1) stays in flight

    #pragma unroll 2
    for (int st = 0; st < NST; ++st) {
        if (st + 1 < NST) {
            Pref Pn = (st + 2 < NST) ? issue(st + 2) : P;   // keep 2 stages in flight
            dq_write(bld[(st + 1) & 1], P, st + 1);          // counted vmcnt wait on P only
            P = Pn;
        }
        compute(bld[st & 1], st);
        asm volatile("s_waitcnt lgkmcnt(0)");                // LDS writes/reads done
        __builtin_amdgcn_s_barrier();                        // global loads NOT drained
    }

    // epilogue: C/D layout col = lane&15, row = (lane>>4)*4 + reg  [m89/m91]
    const int ocol = col0 + bc0;
    const int rb   = wave * 16 + g * 4;
    #pragma unroll
    for (int r = 0; r < 4; ++r) {
        unsafeAtomicAdd(out + (size_t)(rb + r) * OUT_F + ocol,      acc0[r]);
        unsafeAtomicAdd(out + (size_t)(rb + r) * OUT_F + ocol + 16, acc1[r]);
    }
}

extern "C" void kernel_launch(void* const* d_in, const int* in_sizes, int n_in,
                              void* d_out, int out_size, void* d_ws, size_t ws_size,
                              hipStream_t stream) {
    const float* x      = (const float*)d_in[0];
    const int*   wp     = (const int*)  d_in[1];
    const float* wscale = (const float*)d_in[2];
    const float* wzero  = (const float*)d_in[3];
    float*       out    = (float*)d_out;
    uint32_t*    xh     = (uint32_t*)d_ws;   // needs 512 KB of workspace
    (void)in_sizes; (void)n_in; (void)out_size; (void)ws_size;

    prep_kernel<<<dim3(688), dim3(256), 0, stream>>>(x, xh, (float4*)out);
    int4_gemm_kernel<<<dim3(344, 2), dim3(256), 0, stream>>>(wp, wscale, wzero, xh, out);
}